// Round 2
// baseline (91.451 us; speedup 1.0000x reference)
//
#include <hip/hip_runtime.h>

// NFP pooling: out[b,o,i,j] = -sum_c |x[b,c,i+1,j+1] - x[b,c,i+di,j+dj]|
// for the 8 non-center (di,dj) in a 3x3 window. x: (8,128,224,224) f32.
// out: (8,8,222,222) f32.

constexpr int B  = 8;
constexpr int C  = 128;
constexpr int H  = 224;
constexpr int W  = 224;
constexpr int HO = 222;
constexpr int WO = 222;
constexpr int TPR = WO / 2;                 // 111 column-pairs per output row
constexpr int PLANE = H * W;                // 50176 floats per channel plane
constexpr int OPLANE = HO * WO;             // 49284 floats per output plane
constexpr int TOTAL = B * HO * TPR;         // 197,136 threads
constexpr int NBLK  = (TOTAL + 255) / 256;  // 771 blocks

__global__ __launch_bounds__(256)
void nfp_sad_kernel(const float* __restrict__ x, float* __restrict__ out) {
    // Bijective XCD-chunked swizzle (771 % 8 != 0 -> q/r form).
    constexpr int NX = 8, Q = NBLK / NX, Rr = NBLK % NX;
    int bid = blockIdx.x;
    int xcd = bid % NX, idx = bid / NX;
    int sb  = (xcd < Rr) ? xcd * (Q + 1) + idx
                         : Rr * (Q + 1) + (xcd - Rr) * Q + idx;
    int id = sb * 256 + threadIdx.x;
    if (id >= TOTAL) return;

    int t = id % TPR;           // column-pair index: output cols 2t, 2t+1
    int r = id / TPR;
    int i = r % HO;             // output row
    int b = r / HO;             // batch

    // input rows i..i+2, cols 2t..2t+3 (all <= 223, in-bounds; 8B aligned)
    const float* p = x + (size_t)b * C * PLANE + (size_t)i * W + 2 * t;

    float acc[2][8];
#pragma unroll
    for (int q = 0; q < 2; ++q)
#pragma unroll
        for (int o = 0; o < 8; ++o) acc[q][o] = 0.0f;

#pragma unroll 8
    for (int c = 0; c < C; ++c) {
        float2 a0 = *reinterpret_cast<const float2*>(p);
        float2 a1 = *reinterpret_cast<const float2*>(p + 2);
        float2 b0 = *reinterpret_cast<const float2*>(p + W);
        float2 b1 = *reinterpret_cast<const float2*>(p + W + 2);
        float2 c0 = *reinterpret_cast<const float2*>(p + 2 * W);
        float2 c1 = *reinterpret_cast<const float2*>(p + 2 * W + 2);
        p += PLANE;

        float r0[4] = {a0.x, a0.y, a1.x, a1.y};
        float r1[4] = {b0.x, b0.y, b1.x, b1.y};
        float r2[4] = {c0.x, c0.y, c1.x, c1.y};

        // offset order: (0,0),(0,1),(0,2),(1,0),(1,2),(2,0),(2,1),(2,2)
        // shared diff: |r1[1]-r1[2]| feeds (q0,o4) and (q1,o3)
        float dmid = __builtin_fabsf(r1[1] - r1[2]);

        acc[0][0] += __builtin_fabsf(r1[1] - r0[0]);
        acc[0][1] += __builtin_fabsf(r1[1] - r0[1]);
        acc[0][2] += __builtin_fabsf(r1[1] - r0[2]);
        acc[0][3] += __builtin_fabsf(r1[1] - r1[0]);
        acc[0][4] += dmid;
        acc[0][5] += __builtin_fabsf(r1[1] - r2[0]);
        acc[0][6] += __builtin_fabsf(r1[1] - r2[1]);
        acc[0][7] += __builtin_fabsf(r1[1] - r2[2]);

        acc[1][0] += __builtin_fabsf(r1[2] - r0[1]);
        acc[1][1] += __builtin_fabsf(r1[2] - r0[2]);
        acc[1][2] += __builtin_fabsf(r1[2] - r0[3]);
        acc[1][3] += dmid;
        acc[1][4] += __builtin_fabsf(r1[2] - r1[3]);
        acc[1][5] += __builtin_fabsf(r1[2] - r2[1]);
        acc[1][6] += __builtin_fabsf(r1[2] - r2[2]);
        acc[1][7] += __builtin_fabsf(r1[2] - r2[3]);
    }

    float* op = out + (size_t)b * 8 * OPLANE + (size_t)i * WO + 2 * t;
#pragma unroll
    for (int o = 0; o < 8; ++o) {
        float2 v = make_float2(-acc[0][o], -acc[1][o]);
        *reinterpret_cast<float2*>(op + (size_t)o * OPLANE) = v;
    }
}

extern "C" void kernel_launch(void* const* d_in, const int* in_sizes, int n_in,
                              void* d_out, int out_size, void* d_ws, size_t ws_size,
                              hipStream_t stream) {
    const float* x = (const float*)d_in[0];
    float* out = (float*)d_out;
    nfp_sad_kernel<<<NBLK, 256, 0, stream>>>(x, out);
}

// Round 3
// 68.515 us; speedup vs baseline: 1.3348x; 1.3348x over previous
//
#include <hip/hip_runtime.h>

// NFP pooling: out[b,o,i,j] = -sum_c |x[b,c,i+1,j+1] - x[b,c,i+di,j+dj]|
// for the 8 non-center (di,dj) in a 3x3 window. x: (8,128,224,224) f32.
// out: (8,8,222,222) f32.
//
// R3: explicit depth-2 software pipeline over channels (named regs, 3-stage
// rotation unrolled x3) to force ~12 loads in flight per wave. Latency-bound
// fix per R2 counters (VGPR=20 showed compiler didn't pipeline).

constexpr int B  = 8;
constexpr int C  = 128;
constexpr int H  = 224;
constexpr int W  = 224;
constexpr int HO = 222;
constexpr int WO = 222;
constexpr int TPR = WO / 2;                 // 111 column-pairs per output row
constexpr int PLANE = H * W;                // 50176
constexpr int OPLANE = HO * WO;             // 49284
constexpr int TOTAL = B * HO * TPR;         // 197,136 threads
constexpr int NBLK  = (TOTAL + 255) / 256;  // 771 blocks

#define LOAD6(va0, va1, vb0, vb1, vc0, vc1, ptr)                       \
    va0 = *reinterpret_cast<const float2*>(ptr);                       \
    va1 = *reinterpret_cast<const float2*>((ptr) + 2);                 \
    vb0 = *reinterpret_cast<const float2*>((ptr) + W);                 \
    vb1 = *reinterpret_cast<const float2*>((ptr) + W + 2);             \
    vc0 = *reinterpret_cast<const float2*>((ptr) + 2 * W);             \
    vc1 = *reinterpret_cast<const float2*>((ptr) + 2 * W + 2);

// offset order: (0,0),(0,1),(0,2),(1,0),(1,2),(2,0),(2,1),(2,2)
#define COMP(va0, va1, vb0, vb1, vc0, vc1) {                           \
    float x0 = va0.x, x1 = va0.y, x2 = va1.x, x3 = va1.y;              \
    float y0 = vb0.x, y1 = vb0.y, y2 = vb1.x, y3 = vb1.y;              \
    float z0 = vc0.x, z1 = vc0.y, z2 = vc1.x, z3 = vc1.y;              \
    float dm = __builtin_fabsf(y1 - y2);                               \
    a00 += __builtin_fabsf(y1 - x0);  a01 += __builtin_fabsf(y1 - x1); \
    a02 += __builtin_fabsf(y1 - x2);  a03 += __builtin_fabsf(y1 - y0); \
    a04 += dm;                        a05 += __builtin_fabsf(y1 - z0); \
    a06 += __builtin_fabsf(y1 - z1);  a07 += __builtin_fabsf(y1 - z2); \
    a10 += __builtin_fabsf(y2 - x1);  a11 += __builtin_fabsf(y2 - x2); \
    a12 += __builtin_fabsf(y2 - x3);  a13 += dm;                       \
    a14 += __builtin_fabsf(y2 - y3);  a15 += __builtin_fabsf(y2 - z1); \
    a16 += __builtin_fabsf(y2 - z2);  a17 += __builtin_fabsf(y2 - z3); \
}

__global__ __launch_bounds__(256, 1)
void nfp_sad_kernel(const float* __restrict__ x, float* __restrict__ out) {
    int id = blockIdx.x * 256 + threadIdx.x;
    if (id >= TOTAL) return;

    int t = id % TPR;           // column-pair index: output cols 2t, 2t+1
    int r = id / TPR;
    int i = r % HO;             // output row
    int b = r / HO;             // batch

    // input rows i..i+2, cols 2t..2t+3 (all <= 223, in-bounds; 8B aligned)
    const float* p = x + (size_t)b * C * PLANE + (size_t)i * W + 2 * t;

    float a00 = 0, a01 = 0, a02 = 0, a03 = 0, a04 = 0, a05 = 0, a06 = 0, a07 = 0;
    float a10 = 0, a11 = 0, a12 = 0, a13 = 0, a14 = 0, a15 = 0, a16 = 0, a17 = 0;

    // three pipeline stages, named registers only
    float2 Aa0, Aa1, Ab0, Ab1, Ac0, Ac1;
    float2 Ba0, Ba1, Bb0, Bb1, Bc0, Bc1;
    float2 Ca0, Ca1, Cb0, Cb1, Cc0, Cc1;

    LOAD6(Aa0, Aa1, Ab0, Ab1, Ac0, Ac1, p); p += PLANE;   // c = 0
    LOAD6(Ba0, Ba1, Bb0, Bb1, Bc0, Bc1, p); p += PLANE;   // c = 1

    // steady state: 126 channels, 3-stage rotation unrolled x3 (42 iters)
    for (int k = 0; k < (C - 2) / 3; ++k) {
        LOAD6(Ca0, Ca1, Cb0, Cb1, Cc0, Cc1, p); p += PLANE;   // c = 3k+2
        COMP(Aa0, Aa1, Ab0, Ab1, Ac0, Ac1);                   // c = 3k
        LOAD6(Aa0, Aa1, Ab0, Ab1, Ac0, Ac1, p); p += PLANE;   // c = 3k+3
        COMP(Ba0, Ba1, Bb0, Bb1, Bc0, Bc1);                   // c = 3k+1
        LOAD6(Ba0, Ba1, Bb0, Bb1, Bc0, Bc1, p); p += PLANE;   // c = 3k+4
        COMP(Ca0, Ca1, Cb0, Cb1, Cc0, Cc1);                   // c = 3k+2
    }
    COMP(Aa0, Aa1, Ab0, Ab1, Ac0, Ac1);                       // c = 126
    COMP(Ba0, Ba1, Bb0, Bb1, Bc0, Bc1);                       // c = 127

    float* op = out + (size_t)b * 8 * OPLANE + (size_t)i * WO + 2 * t;
    *reinterpret_cast<float2*>(op + 0 * OPLANE) = make_float2(-a00, -a10);
    *reinterpret_cast<float2*>(op + 1 * OPLANE) = make_float2(-a01, -a11);
    *reinterpret_cast<float2*>(op + 2 * OPLANE) = make_float2(-a02, -a12);
    *reinterpret_cast<float2*>(op + 3 * OPLANE) = make_float2(-a03, -a13);
    *reinterpret_cast<float2*>(op + 4 * OPLANE) = make_float2(-a04, -a14);
    *reinterpret_cast<float2*>(op + 5 * OPLANE) = make_float2(-a05, -a15);
    *reinterpret_cast<float2*>(op + 6 * OPLANE) = make_float2(-a06, -a16);
    *reinterpret_cast<float2*>(op + 7 * OPLANE) = make_float2(-a07, -a17);
}

extern "C" void kernel_launch(void* const* d_in, const int* in_sizes, int n_in,
                              void* d_out, int out_size, void* d_ws, size_t ws_size,
                              hipStream_t stream) {
    const float* x = (const float*)d_in[0];
    float* out = (float*)d_out;
    nfp_sad_kernel<<<NBLK, 256, 0, stream>>>(x, out);
}